// Round 14
// baseline (610.346 us; speedup 1.0000x reference)
//
#include <hip/hip_runtime.h>
#include <math.h>

#define GROUPS 32
#define CG 16
#define HH 56
#define WW 56
#define HW (HH*WW)          // 3136
#define BG 1024             // B*GROUPS
#define EPS 1e-5f

#define XWS 60              // s_xw stride; 60%32=28 -> bank spread
#define XHS 57              // s_xh stride; odd -> full bank spread

// phase-A scratch offsets inside s_u
#define U_ROW 0             // CG*HH = 896 row means
#define U_COL 896           // CG*WW = 896 col means
#define U_ST  1792          // CG*9  = 144 per-channel stats
#define U_X2P 1936          // CG*CG = 256 x2 partials [c][o]
#define U_LS1 2192          // 16 sum
#define U_LS2 2208          // 16 sumsq
#define U_SZ  2224

// native clang vector (NOT HIP_vector_type) -- accepted by the nontemporal
// builtin; identical 16-byte layout to float4.
typedef float vf4 __attribute__((ext_vector_type(4)));

// non-temporal float4 store: out is write-once/never-read -> keep it from
// evicting x out of L2/L3 (x is re-read on passes 2 and 3)
static __device__ __forceinline__ void nt_store4(float* p,
        float a, float b, float c, float d)
{
    vf4 v; v.x = a; v.y = b; v.z = c; v.w = d;
    __builtin_nontemporal_store(v, (vf4*)p);
}

// ---------------------------------------------------------------------------
// kF: grand-fused per-instance kernel, 512 threads (8 waves) per block,
// __launch_bounds__(512, 4) (VGPR cap 128; compiles at 64, no spill -- R12).
// R14 = R13 with the nontemporal builtin's type fixed (ext_vector_type).
// Output stores are NON-TEMPORAL so the 205 MB out-stream does not evict
// x (205 MB) from the 256 MB L3 between the kernel's 3 passes.
// Barrier-free BC phase: thread = (channel, 14-row quarter, 8-px strip),
// rolling 4-row register window loaded directly from global; in-wave
// 16-channel butterfly.
// ---------------------------------------------------------------------------
__global__ __launch_bounds__(512, 4) void kF(const float* __restrict__ x,
        const float* __restrict__ w1, const float* __restrict__ b1,
        const float* __restrict__ w3, const float* __restrict__ b3,
        const float* __restrict__ gn_w, const float* __restrict__ gn_b,
        float* __restrict__ out)
{
    const int g = blockIdx.x;
    const int tid = threadIdx.x;
    const float* gx = x + (size_t)g * CG * HW;
    float* og = out + (size_t)g * CG * HW;

    __shared__ float s_u[U_SZ];         // 8896 B A-phase scratch
    __shared__ float s_xh[CG * XHS];    // xh, becomes gh = asc*xh after A6b
    __shared__ float s_xw[CG * XWS];    // xw (padded stride)
    __shared__ float s_wa[CG * 9 + 1];  // a1-folded weights + ab
    __shared__ float s_asc[CG];
    __shared__ float s_bias;

    // ---- A0: a1 = softmax(gn_b); wa[ci][k] = sum_o a1[o] w3[o][ci][k] ----
    if (tid < CG * 9 + 1) {
        float m = gn_b[0];
        #pragma unroll
        for (int c = 1; c < CG; ++c) m = fmaxf(m, gn_b[c]);
        float a1[CG]; float den = 0.f;
        #pragma unroll
        for (int c = 0; c < CG; ++c) { a1[c] = __expf(gn_b[c] - m); den += a1[c]; }
        float inv = 1.f / den;
        if (tid < CG * 9) {
            int ci = tid / 9, k = tid - (tid / 9) * 9;
            float s = 0.f;
            #pragma unroll
            for (int o = 0; o < CG; ++o) s += a1[o] * w3[(size_t)(o * CG + ci) * 9 + k];
            s_wa[tid] = s * inv;
        } else {
            float s = 0.f;
            #pragma unroll
            for (int o = 0; o < CG; ++o) s += a1[o] * b3[o];
            s_wa[CG * 9] = s * inv;
        }
    }

    // ---- A1: pooling, 32-lane group per channel (16 per row-parity) ----
    {
        const int grp  = tid >> 5;      // channel 0..15
        const int lane = tid & 31;
        const int ql   = lane & 15;     // quad index (ql<14 active)
        const int hi   = lane >> 4;     // row parity
        const float* pc = gx + grp * HW;
        float c0 = 0.f, c1 = 0.f, c2 = 0.f, c3 = 0.f;
        for (int row = 0; row < HH; row += 2) {
            const int r = row + hi;
            float4 v = make_float4(0.f, 0.f, 0.f, 0.f);
            if (ql < 14) v = *(const float4*)(pc + r * WW + ql * 4);
            c0 += v.x; c1 += v.y; c2 += v.z; c3 += v.w;
            float rs = (v.x + v.y) + (v.z + v.w);
            rs += __shfl_xor(rs, 8);
            rs += __shfl_xor(rs, 4);
            rs += __shfl_xor(rs, 2);
            rs += __shfl_xor(rs, 1);
            if (ql == 0) s_u[U_ROW + grp * HH + r] = rs * (1.0f / WW);
        }
        // combine the two row-parity halves' column sums
        c0 += __shfl_xor(c0, 16); c1 += __shfl_xor(c1, 16);
        c2 += __shfl_xor(c2, 16); c3 += __shfl_xor(c3, 16);
        if (hi == 0 && ql < 14) {
            s_u[U_COL + grp * WW + ql * 4 + 0] = c0 * (1.0f / HH);
            s_u[U_COL + grp * WW + ql * 4 + 1] = c1 * (1.0f / HH);
            s_u[U_COL + grp * WW + ql * 4 + 2] = c2 * (1.0f / HH);
            s_u[U_COL + grp * WW + ql * 4 + 3] = c3 * (1.0f / HH);
        }
    }
    __syncthreads();   // S1

    // ---- A2: 1x1 channel mix + bias + sigmoid -> s_xh, s_xw ----
    for (int t = tid; t < 2 * CG * HH; t += 512) {
        int hpart = (t < CG * HH);
        int tt = hpart ? t : t - CG * HH;
        int o = tt / HH, i = tt - (tt / HH) * HH;
        float v = b1[o];
        #pragma unroll
        for (int c = 0; c < CG; ++c)
            v += w1[o * CG + c] * (hpart ? s_u[U_ROW + c * HH + i]
                                         : s_u[U_COL + c * WW + i]);
        float sg = 1.f / (1.f + __expf(-v));
        if (hpart) s_xh[o * XHS + i] = sg;
        else       s_xw[o * XWS + i] = sg;
    }

    // ---- A3: per-channel stats for analytic x2sum (threads 0..15) ----
    if (tid < CG) {
        const int c = tid;
        float S = 0.f;
        #pragma unroll
        for (int r = 0; r < HH; ++r) S += s_u[U_ROW + c * HH + r];
        float* st = &s_u[U_ST + c * 9];
        st[0] = S * (float)WW;
        st[1] = (float)WW * s_u[U_ROW + c * HH + HH - 1];
        st[2] = (float)WW * s_u[U_ROW + c * HH];
        st[3] = (float)HH * s_u[U_COL + c * WW + WW - 1];
        st[4] = (float)HH * s_u[U_COL + c * WW];
        const float* p = gx + c * HW;
        st[5] = p[0];
        st[6] = p[WW - 1];
        st[7] = p[(HH - 1) * WW];
        st[8] = p[(HH - 1) * WW + WW - 1];
    }
    __syncthreads();   // S2

    // ---- A4: x2 tap partials, thread (o = tid>>4, c = tid&15), tid<256 ----
    if (tid < 256) {
        const int o = tid >> 4, c = tid & 15;
        const float* wp = w3 + (size_t)(o * CG + c) * 9;
        const float* st = &s_u[U_ST + c * 9];
        float S = st[0];
        float acc = 0.f;
        #pragma unroll
        for (int dy = 0; dy < 3; ++dy) {
            float Rv = (dy == 0) ? st[1] : (dy == 2 ? st[2] : 0.f);
            #pragma unroll
            for (int dx = 0; dx < 3; ++dx) {
                float Cv = (dx == 0) ? st[3] : (dx == 2 ? st[4] : 0.f);
                float T = S - Rv - Cv;
                if (dy != 1 && dx != 1)
                    T += (dy == 0) ? ((dx == 0) ? st[8] : st[7])
                                   : ((dx == 0) ? st[6] : st[5]);
                acc += wp[dy * 3 + dx] * T;
            }
        }
        s_u[U_X2P + c * CG + o] = acc;
    }

    // ---- A5: sum/sumsq of t = gx*xh*xw (pass 2), 32-lane group/channel,
    //      perfectly contiguous quad stream: quad i at float offset 4*i ----
    {
        const int c    = tid >> 5;
        const int lane = tid & 31;
        const float* pc = gx + c * HW;
        float s1 = 0.f, s2 = 0.f;
        for (int i = lane; i < 784; i += 32) {
            int row = i / 14;
            int q   = i - row * 14;
            float4 v = *(const float4*)(pc + i * 4);
            float xh = s_xh[c * XHS + row];
            float t0 = v.x * xh * s_xw[c * XWS + q * 4 + 0];
            float t1 = v.y * xh * s_xw[c * XWS + q * 4 + 1];
            float t2 = v.z * xh * s_xw[c * XWS + q * 4 + 2];
            float t3 = v.w * xh * s_xw[c * XWS + q * 4 + 3];
            s1 += (t0 + t1) + (t2 + t3);
            s2 += (t0 * t0 + t1 * t1) + (t2 * t2 + t3 * t3);
        }
        s1 += __shfl_xor(s1, 16);  s2 += __shfl_xor(s2, 16);
        s1 += __shfl_xor(s1, 8);   s2 += __shfl_xor(s2, 8);
        s1 += __shfl_xor(s1, 4);   s2 += __shfl_xor(s2, 4);
        s1 += __shfl_xor(s1, 2);   s2 += __shfl_xor(s2, 2);
        s1 += __shfl_xor(s1, 1);   s2 += __shfl_xor(s2, 1);
        if (lane == 0) { s_u[U_LS1 + c] = s1; s_u[U_LS2 + c] = s2; }
    }
    __syncthreads();   // S3

    // ---- A6a (threads 0..15): scale/shift, a2 softmax, asc, bias ----
    if (tid < CG) {
        const int o = tid;
        float x2 = (float)HW * b3[o];
        #pragma unroll
        for (int c = 0; c < CG; ++c) x2 += s_u[U_X2P + c * CG + o];

        float mu  = s_u[U_LS1 + o] * (1.0f / HW);
        float var = s_u[U_LS2 + o] * (1.0f / HW) - mu * mu;
        float sc  = gn_w[o] * rsqrtf(var + EPS);
        float sh  = gn_b[o] - mu * sc;

        float v2 = x2 * (1.0f / HW);
        float m = v2;
        #pragma unroll
        for (int off = 8; off; off >>= 1) m = fmaxf(m, __shfl_xor(m, off));
        float e = __expf(v2 - m);
        float den = e;
        #pragma unroll
        for (int off = 8; off; off >>= 1) den += __shfl_xor(den, off);
        float a2 = e / den;

        s_asc[o] = a2 * sc;
        float part = a2 * sh;
        #pragma unroll
        for (int off = 8; off; off >>= 1) part += __shfl_xor(part, off);
        if (o == 0) s_bias = part + s_wa[CG * 9];
    }
    __syncthreads();   // S4

    // ---- A6b: fold asc into s_xh (gh = asc * xh) ----
    for (int t = tid; t < CG * HH; t += 512) {
        int c = t / HH, y = t - (t / HH) * HH;
        s_xh[c * XHS + y] *= s_asc[c];
    }
    __syncthreads();   // S5 -- last barrier in the kernel

    // ---- BC: barrier-free rolling-window conv + epilogue (448 threads) ----
    if (tid < 448) {
        const int cc   = tid & 15;
        const int sp   = tid >> 4;            // 0..27
        const int quart = sp / 7;             // 0..3
        const int x0   = (sp - quart * 7) * 8; // 0,8,..,48
        const int ybase = quart * 14;

        float wreg[9];
        #pragma unroll
        for (int i = 0; i < 9; ++i) wreg[i] = s_wa[cc * 9 + i];
        float xwv[8];
        {
            float4 X0 = *(const float4*)&s_xw[cc * XWS + x0];
            float4 X1 = *(const float4*)&s_xw[cc * XWS + x0 + 4];
            xwv[0] = X0.x; xwv[1] = X0.y; xwv[2] = X0.z; xwv[3] = X0.w;
            xwv[4] = X1.x; xwv[5] = X1.y; xwv[6] = X1.z; xwv[7] = X1.w;
        }
        const float bias = s_bias;
        const float* pc = gx + cc * HW + x0;
        float* oc = og + cc * HW + x0;
        const bool lok = (x0 > 0);
        const bool rok = (x0 < 48);

        float rw1[10], rw2[10], rw3[10], rw4[10];

        #define LOADROW(R, W) do {                                         \
            int r_ = (R);                                                  \
            if (r_ >= 0 && r_ < HH) {                                      \
                const float* bp_ = pc + r_ * WW;                           \
                float4 f1_ = *(const float4*)(bp_);                        \
                float4 f2_ = *(const float4*)(bp_ + 4);                    \
                (W)[0] = lok ? bp_[-1] : 0.f;                              \
                (W)[9] = rok ? bp_[8]  : 0.f;                              \
                (W)[1] = f1_.x; (W)[2] = f1_.y; (W)[3] = f1_.z; (W)[4] = f1_.w; \
                (W)[5] = f2_.x; (W)[6] = f2_.y; (W)[7] = f2_.z; (W)[8] = f2_.w; \
            } else {                                                       \
                _Pragma("unroll")                                          \
                for (int i_ = 0; i_ < 10; ++i_) (W)[i_] = 0.f;             \
            }                                                              \
        } while (0)

        LOADROW(ybase - 1, rw1);
        LOADROW(ybase,     rw2);

        for (int p = 0; p < 7; ++p) {
            const int y0 = ybase + 2 * p;
            LOADROW(y0 + 1, rw3);
            LOADROW(y0 + 2, rw4);
            const float gh0 = s_xh[cc * XHS + y0];
            const float gh1 = s_xh[cc * XHS + y0 + 1];

            float acc0[8], acc1[8];
            #pragma unroll
            for (int j = 0; j < 8; ++j) {
                acc0[j] = wreg[0] * rw1[j] + wreg[1] * rw1[j + 1] + wreg[2] * rw1[j + 2]
                        + wreg[3] * rw2[j] + wreg[4] * rw2[j + 1] + wreg[5] * rw2[j + 2]
                        + wreg[6] * rw3[j] + wreg[7] * rw3[j + 1] + wreg[8] * rw3[j + 2]
                        + gh0 * xwv[j] * rw2[j + 1];
                acc1[j] = wreg[0] * rw2[j] + wreg[1] * rw2[j + 1] + wreg[2] * rw2[j + 2]
                        + wreg[3] * rw3[j] + wreg[4] * rw3[j + 1] + wreg[5] * rw3[j + 2]
                        + wreg[6] * rw4[j] + wreg[7] * rw4[j + 1] + wreg[8] * rw4[j + 2]
                        + gh1 * xwv[j] * rw3[j + 1];
            }

            // butterfly sum across the 16 channels (lane bits 0..3)
            #pragma unroll
            for (int m = 1; m <= 8; m <<= 1) {
                #pragma unroll
                for (int j = 0; j < 8; ++j) {
                    acc0[j] += __shfl_xor(acc0[j], m);
                    acc1[j] += __shfl_xor(acc1[j], m);
                }
            }

            float* o0 = oc + y0 * WW;
            float* o1 = o0 + WW;
            nt_store4(o0,
                rw2[1] * (1.f / (1.f + __expf(-(acc0[0] + bias)))),
                rw2[2] * (1.f / (1.f + __expf(-(acc0[1] + bias)))),
                rw2[3] * (1.f / (1.f + __expf(-(acc0[2] + bias)))),
                rw2[4] * (1.f / (1.f + __expf(-(acc0[3] + bias)))));
            nt_store4(o0 + 4,
                rw2[5] * (1.f / (1.f + __expf(-(acc0[4] + bias)))),
                rw2[6] * (1.f / (1.f + __expf(-(acc0[5] + bias)))),
                rw2[7] * (1.f / (1.f + __expf(-(acc0[6] + bias)))),
                rw2[8] * (1.f / (1.f + __expf(-(acc0[7] + bias)))));
            nt_store4(o1,
                rw3[1] * (1.f / (1.f + __expf(-(acc1[0] + bias)))),
                rw3[2] * (1.f / (1.f + __expf(-(acc1[1] + bias)))),
                rw3[3] * (1.f / (1.f + __expf(-(acc1[2] + bias)))),
                rw3[4] * (1.f / (1.f + __expf(-(acc1[3] + bias)))));
            nt_store4(o1 + 4,
                rw3[5] * (1.f / (1.f + __expf(-(acc1[4] + bias)))),
                rw3[6] * (1.f / (1.f + __expf(-(acc1[5] + bias)))),
                rw3[7] * (1.f / (1.f + __expf(-(acc1[6] + bias)))),
                rw3[8] * (1.f / (1.f + __expf(-(acc1[7] + bias)))));

            // roll the window by 2 rows
            #pragma unroll
            for (int i = 0; i < 10; ++i) { rw1[i] = rw3[i]; rw2[i] = rw4[i]; }
        }
        #undef LOADROW
    }
}

// ---------------------------------------------------------------------------
extern "C" void kernel_launch(void* const* d_in, const int* in_sizes, int n_in,
                              void* d_out, int out_size, void* d_ws, size_t ws_size,
                              hipStream_t stream)
{
    const float* x    = (const float*)d_in[0];
    const float* w1   = (const float*)d_in[1];
    const float* b1   = (const float*)d_in[2];
    const float* w3   = (const float*)d_in[3];
    const float* b3   = (const float*)d_in[4];
    const float* gn_w = (const float*)d_in[5];
    const float* gn_b = (const float*)d_in[6];
    float* out = (float*)d_out;
    (void)d_ws; (void)ws_size;

    kF<<<BG, 512, 0, stream>>>(x, w1, b1, w3, b3, gn_w, gn_b, out);
}

// Round 15
// 463.037 us; speedup vs baseline: 1.3181x; 1.3181x over previous
//
#include <hip/hip_runtime.h>
#include <math.h>

#define GROUPS 32
#define CG 16
#define HH 56
#define WW 56
#define HW (HH*WW)          // 3136
#define BG 1024             // B*GROUPS
#define EPS 1e-5f

#define XWS 60              // s_xw stride; 60%32=28 -> bank spread
#define XHS 57              // s_xh stride; odd -> full bank spread

// phase-A scratch offsets inside s_u
#define U_ROW 0             // CG*HH = 896 row means
#define U_COL 896           // CG*WW = 896 col means
#define U_ST  1792          // CG*9  = 144 per-channel stats
#define U_X2P 1936          // CG*CG = 256 x2 partials [c][o]
#define U_LS1 2192          // 16 sum
#define U_LS2 2208          // 16 sumsq
#define U_SZ  2224

// ---------------------------------------------------------------------------
// kF: grand-fused per-instance kernel, 512 threads (8 waves) per block,
// __launch_bounds__(512, 4) (VGPR cap 128; compiles at 64, no spill -- R12).
// R15 changes vs R12:
//  - NT stores REVERTED (R14: 2x write amplification from partial-line
//    DRAM writes; FETCH unchanged -> out-eviction theory refuted)
//  - A1: two row-pairs per iteration -> two independent shfl-reduce chains
//  - A5: paired quad streams (i, i+32) -> two independent load/mul chains
// Barrier-free BC phase unchanged: thread = (channel, 14-row quarter,
// 8-px strip), rolling 4-row register window from global, in-wave butterfly.
// ---------------------------------------------------------------------------
__global__ __launch_bounds__(512, 4) void kF(const float* __restrict__ x,
        const float* __restrict__ w1, const float* __restrict__ b1,
        const float* __restrict__ w3, const float* __restrict__ b3,
        const float* __restrict__ gn_w, const float* __restrict__ gn_b,
        float* __restrict__ out)
{
    const int g = blockIdx.x;
    const int tid = threadIdx.x;
    const float* gx = x + (size_t)g * CG * HW;
    float* og = out + (size_t)g * CG * HW;

    __shared__ float s_u[U_SZ];         // 8896 B A-phase scratch
    __shared__ float s_xh[CG * XHS];    // xh, becomes gh = asc*xh after A6b
    __shared__ float s_xw[CG * XWS];    // xw (padded stride)
    __shared__ float s_wa[CG * 9 + 1];  // a1-folded weights + ab
    __shared__ float s_asc[CG];
    __shared__ float s_bias;

    // ---- A0: a1 = softmax(gn_b); wa[ci][k] = sum_o a1[o] w3[o][ci][k] ----
    if (tid < CG * 9 + 1) {
        float m = gn_b[0];
        #pragma unroll
        for (int c = 1; c < CG; ++c) m = fmaxf(m, gn_b[c]);
        float a1[CG]; float den = 0.f;
        #pragma unroll
        for (int c = 0; c < CG; ++c) { a1[c] = __expf(gn_b[c] - m); den += a1[c]; }
        float inv = 1.f / den;
        if (tid < CG * 9) {
            int ci = tid / 9, k = tid - (tid / 9) * 9;
            float s = 0.f;
            #pragma unroll
            for (int o = 0; o < CG; ++o) s += a1[o] * w3[(size_t)(o * CG + ci) * 9 + k];
            s_wa[tid] = s * inv;
        } else {
            float s = 0.f;
            #pragma unroll
            for (int o = 0; o < CG; ++o) s += a1[o] * b3[o];
            s_wa[CG * 9] = s * inv;
        }
    }

    // ---- A1: pooling, 32-lane group per channel, 2 row-pairs/iter (ILP2) ----
    {
        const int grp  = tid >> 5;      // channel 0..15
        const int lane = tid & 31;
        const int ql   = lane & 15;     // quad index (ql<14 active)
        const int hi   = lane >> 4;     // row parity
        const float* pc = gx + grp * HW;
        float c0 = 0.f, c1 = 0.f, c2 = 0.f, c3 = 0.f;
        for (int row = 0; row < HH; row += 4) {
            const int r1 = row + hi;
            const int r2 = row + 2 + hi;
            float4 va = make_float4(0.f, 0.f, 0.f, 0.f);
            float4 vb = va;
            if (ql < 14) {
                va = *(const float4*)(pc + r1 * WW + ql * 4);
                vb = *(const float4*)(pc + r2 * WW + ql * 4);
            }
            c0 += va.x + vb.x; c1 += va.y + vb.y;
            c2 += va.z + vb.z; c3 += va.w + vb.w;
            float ra = (va.x + va.y) + (va.z + va.w);
            float rb = (vb.x + vb.y) + (vb.z + vb.w);
            ra += __shfl_xor(ra, 8);  rb += __shfl_xor(rb, 8);
            ra += __shfl_xor(ra, 4);  rb += __shfl_xor(rb, 4);
            ra += __shfl_xor(ra, 2);  rb += __shfl_xor(rb, 2);
            ra += __shfl_xor(ra, 1);  rb += __shfl_xor(rb, 1);
            if (ql == 0) {
                s_u[U_ROW + grp * HH + r1] = ra * (1.0f / WW);
                s_u[U_ROW + grp * HH + r2] = rb * (1.0f / WW);
            }
        }
        // combine the two row-parity halves' column sums
        c0 += __shfl_xor(c0, 16); c1 += __shfl_xor(c1, 16);
        c2 += __shfl_xor(c2, 16); c3 += __shfl_xor(c3, 16);
        if (hi == 0 && ql < 14) {
            s_u[U_COL + grp * WW + ql * 4 + 0] = c0 * (1.0f / HH);
            s_u[U_COL + grp * WW + ql * 4 + 1] = c1 * (1.0f / HH);
            s_u[U_COL + grp * WW + ql * 4 + 2] = c2 * (1.0f / HH);
            s_u[U_COL + grp * WW + ql * 4 + 3] = c3 * (1.0f / HH);
        }
    }
    __syncthreads();   // S1

    // ---- A2: 1x1 channel mix + bias + sigmoid -> s_xh, s_xw ----
    for (int t = tid; t < 2 * CG * HH; t += 512) {
        int hpart = (t < CG * HH);
        int tt = hpart ? t : t - CG * HH;
        int o = tt / HH, i = tt - (tt / HH) * HH;
        float v = b1[o];
        #pragma unroll
        for (int c = 0; c < CG; ++c)
            v += w1[o * CG + c] * (hpart ? s_u[U_ROW + c * HH + i]
                                         : s_u[U_COL + c * WW + i]);
        float sg = 1.f / (1.f + __expf(-v));
        if (hpart) s_xh[o * XHS + i] = sg;
        else       s_xw[o * XWS + i] = sg;
    }

    // ---- A3: per-channel stats for analytic x2sum (threads 0..15) ----
    if (tid < CG) {
        const int c = tid;
        float S = 0.f;
        #pragma unroll
        for (int r = 0; r < HH; ++r) S += s_u[U_ROW + c * HH + r];
        float* st = &s_u[U_ST + c * 9];
        st[0] = S * (float)WW;
        st[1] = (float)WW * s_u[U_ROW + c * HH + HH - 1];
        st[2] = (float)WW * s_u[U_ROW + c * HH];
        st[3] = (float)HH * s_u[U_COL + c * WW + WW - 1];
        st[4] = (float)HH * s_u[U_COL + c * WW];
        const float* p = gx + c * HW;
        st[5] = p[0];
        st[6] = p[WW - 1];
        st[7] = p[(HH - 1) * WW];
        st[8] = p[(HH - 1) * WW + WW - 1];
    }
    __syncthreads();   // S2

    // ---- A4: x2 tap partials, thread (o = tid>>4, c = tid&15), tid<256 ----
    if (tid < 256) {
        const int o = tid >> 4, c = tid & 15;
        const float* wp = w3 + (size_t)(o * CG + c) * 9;
        const float* st = &s_u[U_ST + c * 9];
        float S = st[0];
        float acc = 0.f;
        #pragma unroll
        for (int dy = 0; dy < 3; ++dy) {
            float Rv = (dy == 0) ? st[1] : (dy == 2 ? st[2] : 0.f);
            #pragma unroll
            for (int dx = 0; dx < 3; ++dx) {
                float Cv = (dx == 0) ? st[3] : (dx == 2 ? st[4] : 0.f);
                float T = S - Rv - Cv;
                if (dy != 1 && dx != 1)
                    T += (dy == 0) ? ((dx == 0) ? st[8] : st[7])
                                   : ((dx == 0) ? st[6] : st[5]);
                acc += wp[dy * 3 + dx] * T;
            }
        }
        s_u[U_X2P + c * CG + o] = acc;
    }

    // ---- A5: sum/sumsq of t = gx*xh*xw (pass 2), 32-lane group/channel,
    //      paired quad streams (i, i+32) for 2 independent chains ----
    {
        const int c    = tid >> 5;
        const int lane = tid & 31;
        const float* pc = gx + c * HW;
        float s1 = 0.f, s2 = 0.f;
        int i = lane;
        for (; i + 32 < 784; i += 64) {
            const int j = i + 32;
            int rowA = i / 14, qA = i - rowA * 14;
            int rowB = j / 14, qB = j - rowB * 14;
            float4 vA = *(const float4*)(pc + i * 4);
            float4 vB = *(const float4*)(pc + j * 4);
            float xhA = s_xh[c * XHS + rowA];
            float xhB = s_xh[c * XHS + rowB];
            float a0 = vA.x * xhA * s_xw[c * XWS + qA * 4 + 0];
            float a1 = vA.y * xhA * s_xw[c * XWS + qA * 4 + 1];
            float a2 = vA.z * xhA * s_xw[c * XWS + qA * 4 + 2];
            float a3 = vA.w * xhA * s_xw[c * XWS + qA * 4 + 3];
            float b0 = vB.x * xhB * s_xw[c * XWS + qB * 4 + 0];
            float b1v = vB.y * xhB * s_xw[c * XWS + qB * 4 + 1];
            float b2 = vB.z * xhB * s_xw[c * XWS + qB * 4 + 2];
            float b3v = vB.w * xhB * s_xw[c * XWS + qB * 4 + 3];
            s1 += ((a0 + a1) + (a2 + a3)) + ((b0 + b1v) + (b2 + b3v));
            s2 += ((a0 * a0 + a1 * a1) + (a2 * a2 + a3 * a3))
                + ((b0 * b0 + b1v * b1v) + (b2 * b2 + b3v * b3v));
        }
        for (; i < 784; i += 32) {
            int row = i / 14, q = i - row * 14;
            float4 v = *(const float4*)(pc + i * 4);
            float xh = s_xh[c * XHS + row];
            float t0 = v.x * xh * s_xw[c * XWS + q * 4 + 0];
            float t1 = v.y * xh * s_xw[c * XWS + q * 4 + 1];
            float t2 = v.z * xh * s_xw[c * XWS + q * 4 + 2];
            float t3 = v.w * xh * s_xw[c * XWS + q * 4 + 3];
            s1 += (t0 + t1) + (t2 + t3);
            s2 += (t0 * t0 + t1 * t1) + (t2 * t2 + t3 * t3);
        }
        s1 += __shfl_xor(s1, 16);  s2 += __shfl_xor(s2, 16);
        s1 += __shfl_xor(s1, 8);   s2 += __shfl_xor(s2, 8);
        s1 += __shfl_xor(s1, 4);   s2 += __shfl_xor(s2, 4);
        s1 += __shfl_xor(s1, 2);   s2 += __shfl_xor(s2, 2);
        s1 += __shfl_xor(s1, 1);   s2 += __shfl_xor(s2, 1);
        if (lane == 0) { s_u[U_LS1 + c] = s1; s_u[U_LS2 + c] = s2; }
    }
    __syncthreads();   // S3

    // ---- A6a (threads 0..15): scale/shift, a2 softmax, asc, bias ----
    if (tid < CG) {
        const int o = tid;
        float x2 = (float)HW * b3[o];
        #pragma unroll
        for (int c = 0; c < CG; ++c) x2 += s_u[U_X2P + c * CG + o];

        float mu  = s_u[U_LS1 + o] * (1.0f / HW);
        float var = s_u[U_LS2 + o] * (1.0f / HW) - mu * mu;
        float sc  = gn_w[o] * rsqrtf(var + EPS);
        float sh  = gn_b[o] - mu * sc;

        float v2 = x2 * (1.0f / HW);
        float m = v2;
        #pragma unroll
        for (int off = 8; off; off >>= 1) m = fmaxf(m, __shfl_xor(m, off));
        float e = __expf(v2 - m);
        float den = e;
        #pragma unroll
        for (int off = 8; off; off >>= 1) den += __shfl_xor(den, off);
        float a2 = e / den;

        s_asc[o] = a2 * sc;
        float part = a2 * sh;
        #pragma unroll
        for (int off = 8; off; off >>= 1) part += __shfl_xor(part, off);
        if (o == 0) s_bias = part + s_wa[CG * 9];
    }
    __syncthreads();   // S4

    // ---- A6b: fold asc into s_xh (gh = asc * xh) ----
    for (int t = tid; t < CG * HH; t += 512) {
        int c = t / HH, y = t - (t / HH) * HH;
        s_xh[c * XHS + y] *= s_asc[c];
    }
    __syncthreads();   // S5 -- last barrier in the kernel

    // ---- BC: barrier-free rolling-window conv + epilogue (448 threads) ----
    if (tid < 448) {
        const int cc   = tid & 15;
        const int sp   = tid >> 4;            // 0..27
        const int quart = sp / 7;             // 0..3
        const int x0   = (sp - quart * 7) * 8; // 0,8,..,48
        const int ybase = quart * 14;

        float wreg[9];
        #pragma unroll
        for (int i = 0; i < 9; ++i) wreg[i] = s_wa[cc * 9 + i];
        float xwv[8];
        {
            float4 X0 = *(const float4*)&s_xw[cc * XWS + x0];
            float4 X1 = *(const float4*)&s_xw[cc * XWS + x0 + 4];
            xwv[0] = X0.x; xwv[1] = X0.y; xwv[2] = X0.z; xwv[3] = X0.w;
            xwv[4] = X1.x; xwv[5] = X1.y; xwv[6] = X1.z; xwv[7] = X1.w;
        }
        const float bias = s_bias;
        const float* pc = gx + cc * HW + x0;
        float* oc = og + cc * HW + x0;
        const bool lok = (x0 > 0);
        const bool rok = (x0 < 48);

        float rw1[10], rw2[10], rw3[10], rw4[10];

        #define LOADROW(R, W) do {                                         \
            int r_ = (R);                                                  \
            if (r_ >= 0 && r_ < HH) {                                      \
                const float* bp_ = pc + r_ * WW;                           \
                float4 f1_ = *(const float4*)(bp_);                        \
                float4 f2_ = *(const float4*)(bp_ + 4);                    \
                (W)[0] = lok ? bp_[-1] : 0.f;                              \
                (W)[9] = rok ? bp_[8]  : 0.f;                              \
                (W)[1] = f1_.x; (W)[2] = f1_.y; (W)[3] = f1_.z; (W)[4] = f1_.w; \
                (W)[5] = f2_.x; (W)[6] = f2_.y; (W)[7] = f2_.z; (W)[8] = f2_.w; \
            } else {                                                       \
                _Pragma("unroll")                                          \
                for (int i_ = 0; i_ < 10; ++i_) (W)[i_] = 0.f;             \
            }                                                              \
        } while (0)

        LOADROW(ybase - 1, rw1);
        LOADROW(ybase,     rw2);

        for (int p = 0; p < 7; ++p) {
            const int y0 = ybase + 2 * p;
            LOADROW(y0 + 1, rw3);
            LOADROW(y0 + 2, rw4);
            const float gh0 = s_xh[cc * XHS + y0];
            const float gh1 = s_xh[cc * XHS + y0 + 1];

            float acc0[8], acc1[8];
            #pragma unroll
            for (int j = 0; j < 8; ++j) {
                acc0[j] = wreg[0] * rw1[j] + wreg[1] * rw1[j + 1] + wreg[2] * rw1[j + 2]
                        + wreg[3] * rw2[j] + wreg[4] * rw2[j + 1] + wreg[5] * rw2[j + 2]
                        + wreg[6] * rw3[j] + wreg[7] * rw3[j + 1] + wreg[8] * rw3[j + 2]
                        + gh0 * xwv[j] * rw2[j + 1];
                acc1[j] = wreg[0] * rw2[j] + wreg[1] * rw2[j + 1] + wreg[2] * rw2[j + 2]
                        + wreg[3] * rw3[j] + wreg[4] * rw3[j + 1] + wreg[5] * rw3[j + 2]
                        + wreg[6] * rw4[j] + wreg[7] * rw4[j + 1] + wreg[8] * rw4[j + 2]
                        + gh1 * xwv[j] * rw3[j + 1];
            }

            // butterfly sum across the 16 channels (lane bits 0..3)
            #pragma unroll
            for (int m = 1; m <= 8; m <<= 1) {
                #pragma unroll
                for (int j = 0; j < 8; ++j) {
                    acc0[j] += __shfl_xor(acc0[j], m);
                    acc1[j] += __shfl_xor(acc1[j], m);
                }
            }

            float* o0 = oc + y0 * WW;
            float* o1 = o0 + WW;
            *(float4*)(o0) = make_float4(
                rw2[1] * (1.f / (1.f + __expf(-(acc0[0] + bias)))),
                rw2[2] * (1.f / (1.f + __expf(-(acc0[1] + bias)))),
                rw2[3] * (1.f / (1.f + __expf(-(acc0[2] + bias)))),
                rw2[4] * (1.f / (1.f + __expf(-(acc0[3] + bias)))));
            *(float4*)(o0 + 4) = make_float4(
                rw2[5] * (1.f / (1.f + __expf(-(acc0[4] + bias)))),
                rw2[6] * (1.f / (1.f + __expf(-(acc0[5] + bias)))),
                rw2[7] * (1.f / (1.f + __expf(-(acc0[6] + bias)))),
                rw2[8] * (1.f / (1.f + __expf(-(acc0[7] + bias)))));
            *(float4*)(o1) = make_float4(
                rw3[1] * (1.f / (1.f + __expf(-(acc1[0] + bias)))),
                rw3[2] * (1.f / (1.f + __expf(-(acc1[1] + bias)))),
                rw3[3] * (1.f / (1.f + __expf(-(acc1[2] + bias)))),
                rw3[4] * (1.f / (1.f + __expf(-(acc1[3] + bias)))));
            *(float4*)(o1 + 4) = make_float4(
                rw3[5] * (1.f / (1.f + __expf(-(acc1[4] + bias)))),
                rw3[6] * (1.f / (1.f + __expf(-(acc1[5] + bias)))),
                rw3[7] * (1.f / (1.f + __expf(-(acc1[6] + bias)))),
                rw3[8] * (1.f / (1.f + __expf(-(acc1[7] + bias)))));

            // roll the window by 2 rows
            #pragma unroll
            for (int i = 0; i < 10; ++i) { rw1[i] = rw3[i]; rw2[i] = rw4[i]; }
        }
        #undef LOADROW
    }
}

// ---------------------------------------------------------------------------
extern "C" void kernel_launch(void* const* d_in, const int* in_sizes, int n_in,
                              void* d_out, int out_size, void* d_ws, size_t ws_size,
                              hipStream_t stream)
{
    const float* x    = (const float*)d_in[0];
    const float* w1   = (const float*)d_in[1];
    const float* b1   = (const float*)d_in[2];
    const float* w3   = (const float*)d_in[3];
    const float* b3   = (const float*)d_in[4];
    const float* gn_w = (const float*)d_in[5];
    const float* gn_b = (const float*)d_in[6];
    float* out = (float*)d_out;
    (void)d_ws; (void)ws_size;

    kF<<<BG, 512, 0, stream>>>(x, w1, b1, w3, b3, gn_w, gn_b, out);
}